// Round 1
// baseline (883.150 us; speedup 1.0000x reference)
//
#include <hip/hip_runtime.h>
#include <hip/hip_bf16.h>

#define D 128

typedef short short8 __attribute__((ext_vector_type(8)));
typedef float f32x4 __attribute__((ext_vector_type(4)));
typedef unsigned short u16;

static __device__ __forceinline__ u16 f2bf(float f) {
  union { float f; unsigned u; } v; v.f = f;
  unsigned r = v.u + 0x7FFF + ((v.u >> 16) & 1);  // round-to-nearest-even
  return (u16)(r >> 16);
}

// ---------- CSR build ----------
__global__ void count_deg_kernel(const int* __restrict__ dst, int* __restrict__ deg, int E) {
  int e = blockIdx.x * 256 + threadIdx.x;
  if (e < E) atomicAdd(&deg[dst[e]], 1);
}

__global__ void scan_kernel(const int* __restrict__ deg, int* __restrict__ rowptr,
                            int* __restrict__ cursor, int n) {
  __shared__ int psum[256];
  int t = threadIdx.x;
  int chunk = (n + 255) / 256;
  int lo = t * chunk, hi = min(lo + chunk, n);
  int s = 0;
  for (int i = lo; i < hi; ++i) s += deg[i];
  psum[t] = s;
  __syncthreads();
  for (int off = 1; off < 256; off <<= 1) {
    int v = (t >= off) ? psum[t - off] : 0;
    __syncthreads();
    psum[t] += v;
    __syncthreads();
  }
  int base = psum[t] - s;  // exclusive prefix of this thread's chunk
  for (int i = lo; i < hi; ++i) {
    rowptr[i] = base; cursor[i] = base; base += deg[i];
  }
  if (t == 255) rowptr[n] = base;  // total = E
}

__global__ void fill_csr_kernel(const int* __restrict__ src, const int* __restrict__ dst,
                                int* __restrict__ cursor, int* __restrict__ colidx, int E) {
  int e = blockIdx.x * 256 + threadIdx.x;
  if (e < E) {
    int p = atomicAdd(&cursor[dst[e]], 1);
    colidx[p] = src[e];
  }
}

// ---------- weight prep: bf16, transposed Wt[n][k] with k-stride 136 (pad) ----------
__global__ void convert_weights_kernel(const float* __restrict__ W1, const float* __restrict__ W2,
                                       u16* __restrict__ W1t, u16* __restrict__ W2t, int L) {
  int idx = blockIdx.x * 256 + threadIdx.x;
  int total = L * D * D;
  if (idx >= total) return;
  int l = idx / (D * D);
  int rem = idx - l * (D * D);
  int nn = rem >> 7, kk = rem & 127;
  size_t s = (size_t)l * D * D + (size_t)kk * D + nn;
  size_t d = (size_t)l * 128 * 136 + (size_t)nn * 136 + kk;
  W1t[d] = f2bf(W1[s]);
  W2t[d] = f2bf(W2[s]);
}

// ---------- aggregation: z = h + sum_{j->i} h[j], written as bf16 ----------
__global__ __launch_bounds__(256) void aggregate_kernel(
    const float* __restrict__ h, const int* __restrict__ rowptr,
    const int* __restrict__ colidx, u16* __restrict__ zb, int N) {
  int node = blockIdx.x * 4 + (threadIdx.x >> 6);
  if (node >= N) return;
  int lane = threadIdx.x & 63;
  const float2* hp = (const float2*)h;
  float2 acc = hp[(size_t)node * 64 + lane];
  int s = rowptr[node], e = rowptr[node + 1];
  for (int k = s; k < e; ++k) {
    int j = colidx[k];
    float2 v = hp[(size_t)j * 64 + lane];
    acc.x += v.x; acc.y += v.y;
  }
  ushort2 o; o.x = f2bf(acc.x); o.y = f2bf(acc.y);
  ((ushort2*)zb)[(size_t)node * 64 + lane] = o;
}

// ---------- fused GEMM + bias + relu: out = relu(A @ W + b) ----------
// A: [N,128] bf16 row-major. Wt: [128][136] bf16 (Wt[n][k] = W[k][n]).
// Block: 256 thr = 4 waves; each wave does 16 rows x 128 cols via 16x16x32 MFMA.
template <int OUT_BF16>
__global__ __launch_bounds__(256) void mlp_gemm_kernel(
    const u16* __restrict__ A, const u16* __restrict__ Wt,
    const float* __restrict__ bias, void* __restrict__ out, int nrows) {
  __shared__ __attribute__((aligned(16))) u16 ldsW[128 * 136];
  {
    const unsigned* s = (const unsigned*)Wt;
    unsigned* d = (unsigned*)ldsW;
    for (int i = threadIdx.x; i < 128 * 136 / 2; i += 256) d[i] = s[i];
  }
  __syncthreads();
  int wave = threadIdx.x >> 6, lane = threadIdx.x & 63;
  int quad = lane >> 4, l16 = lane & 15;
  int row0 = blockIdx.x * 64 + wave * 16;
  int mc = min(row0 + l16, nrows - 1);

  f32x4 acc[8];
  f32x4 zero = {0.f, 0.f, 0.f, 0.f};
#pragma unroll
  for (int nt = 0; nt < 8; ++nt) acc[nt] = zero;

#pragma unroll
  for (int kt = 0; kt < 4; ++kt) {
    short8 a = *(const short8*)(A + (size_t)mc * D + kt * 32 + quad * 8);
#pragma unroll
    for (int nt = 0; nt < 8; ++nt) {
      short8 b = *(const short8*)(ldsW + (nt * 16 + l16) * 136 + kt * 32 + quad * 8);
      acc[nt] = __builtin_amdgcn_mfma_f32_16x16x32_bf16(a, b, acc[nt], 0, 0, 0);
    }
  }

#pragma unroll
  for (int nt = 0; nt < 8; ++nt) {
    int col = nt * 16 + l16;
    float bv = bias[col];
#pragma unroll
    for (int r = 0; r < 4; ++r) {
      int row = row0 + quad * 4 + r;
      if (row < nrows) {
        float v = fmaxf(acc[nt][r] + bv, 0.f);
        if (OUT_BF16) ((u16*)out)[(size_t)row * D + col] = f2bf(v);
        else          ((float*)out)[(size_t)row * D + col] = v;
      }
    }
  }
}

// ---------- pooling: per-node dot with Wh, segment mean, + bh ----------
__global__ __launch_bounds__(256) void pool_dot_kernel(
    const float* __restrict__ h, const float* __restrict__ Wh,
    const int* __restrict__ batch, float* __restrict__ gsum,
    int* __restrict__ gcnt, int N) {
  int wid = (blockIdx.x * 256 + threadIdx.x) >> 6;
  int lane = threadIdx.x & 63;
  int nw = (gridDim.x * 256) >> 6;
  float2 w = ((const float2*)Wh)[lane];
  for (int node = wid; node < N; node += nw) {
    float2 v = ((const float2*)(h + (size_t)node * D))[lane];
    float d = v.x * w.x + v.y * w.y;
#pragma unroll
    for (int off = 32; off > 0; off >>= 1) d += __shfl_down(d, off, 64);
    if (lane == 0) {
      int b = batch[node];
      atomicAdd(&gsum[b], d);
      atomicAdd(&gcnt[b], 1);
    }
  }
}

__global__ void pool_final_kernel(const float* __restrict__ gsum, const int* __restrict__ gcnt,
                                  const float* __restrict__ bh, float* __restrict__ out, int G) {
  int g = blockIdx.x * 256 + threadIdx.x;
  if (g < G) out[g] = gsum[g] / fmaxf((float)gcnt[g], 1.f) + bh[0];
}

extern "C" void kernel_launch(void* const* d_in, const int* in_sizes, int n_in,
                              void* d_out, int out_size, void* d_ws, size_t ws_size,
                              hipStream_t stream) {
  const float* x   = (const float*)d_in[0];
  const int* eidx  = (const int*)d_in[1];
  const int* batch = (const int*)d_in[2];
  const float* W1s = (const float*)d_in[3];
  const float* b1s = (const float*)d_in[4];
  const float* W2s = (const float*)d_in[5];
  const float* b2s = (const float*)d_in[6];
  const float* Wh  = (const float*)d_in[7];
  const float* bh  = (const float*)d_in[8];
  float* out = (float*)d_out;

  int N = in_sizes[0] / D;
  int E = in_sizes[1] / 2;
  int G = out_size;
  int L = in_sizes[3] / (D * D);

  const int* src = eidx;
  const int* dst = eidx + E;

  char* p = (char*)d_ws;
  auto alloc = [&](size_t b) { char* r = p; p += (b + 255) & ~(size_t)255; return r; };
  float* h     = (float*)alloc((size_t)N * D * 4);
  u16*   zb    = (u16*)  alloc((size_t)N * D * 2);
  u16*   y     = (u16*)  alloc((size_t)N * D * 2);
  int*   deg   = (int*)  alloc((size_t)N * 4);
  int*   rowptr= (int*)  alloc((size_t)(N + 1) * 4);
  int*   cursor= (int*)  alloc((size_t)N * 4);
  int*   colidx= (int*)  alloc((size_t)E * 4);
  u16*   W1t   = (u16*)  alloc((size_t)L * 128 * 136 * 2);
  u16*   W2t   = (u16*)  alloc((size_t)L * 128 * 136 * 2);
  float* gsum  = (float*)alloc((size_t)G * 4);
  int*   gcnt  = (int*)  alloc((size_t)G * 4);

  hipMemsetAsync(deg, 0, (size_t)N * 4, stream);
  hipMemsetAsync(gsum, 0, (size_t)G * 4, stream);
  hipMemsetAsync(gcnt, 0, (size_t)G * 4, stream);

  count_deg_kernel<<<(E + 255) / 256, 256, 0, stream>>>(dst, deg, E);
  scan_kernel<<<1, 256, 0, stream>>>(deg, rowptr, cursor, N);
  fill_csr_kernel<<<(E + 255) / 256, 256, 0, stream>>>(src, dst, cursor, colidx, E);
  convert_weights_kernel<<<(L * D * D + 255) / 256, 256, 0, stream>>>(W1s, W2s, W1t, W2t, L);

  int gemm_blocks = (N + 63) / 64;
  for (int l = 0; l < L; ++l) {
    const float* hin = (l == 0) ? x : h;
    aggregate_kernel<<<(N + 3) / 4, 256, 0, stream>>>(hin, rowptr, colidx, zb, N);
    mlp_gemm_kernel<1><<<gemm_blocks, 256, 0, stream>>>(
        zb, W1t + (size_t)l * 128 * 136, b1s + (size_t)l * D, (void*)y, N);
    mlp_gemm_kernel<0><<<gemm_blocks, 256, 0, stream>>>(
        y, W2t + (size_t)l * 128 * 136, b2s + (size_t)l * D, (void*)h, N);
  }
  pool_dot_kernel<<<512, 256, 0, stream>>>(h, Wh, batch, gsum, gcnt, N);
  pool_final_kernel<<<(G + 255) / 256, 256, 0, stream>>>(gsum, gcnt, bh, out, G);
}

// Round 2
// 600.703 us; speedup vs baseline: 1.4702x; 1.4702x over previous
//
#include <hip/hip_runtime.h>
#include <hip/hip_bf16.h>

#define D 128

typedef short short8 __attribute__((ext_vector_type(8)));
typedef float f32x4 __attribute__((ext_vector_type(4)));
typedef unsigned short u16;

static __device__ __forceinline__ u16 f2bf(float f) {
  union { float f; unsigned u; } v; v.f = f;
  unsigned r = v.u + 0x7FFF + ((v.u >> 16) & 1);  // round-to-nearest-even
  return (u16)(r >> 16);
}

// ---------- CSR build ----------
__global__ void count_deg_kernel(const int* __restrict__ dst, int* __restrict__ deg, int E) {
  int e = blockIdx.x * 256 + threadIdx.x;
  if (e < E) atomicAdd(&deg[dst[e]], 1);
}

// hierarchical scan: per-block inclusive scan + block totals
__global__ void block_scan_kernel(const int* __restrict__ deg, int* __restrict__ lscan,
                                  int* __restrict__ partials, int n) {
  __shared__ int tmp[256];
  int t = threadIdx.x;
  int i = blockIdx.x * 256 + t;
  int v = (i < n) ? deg[i] : 0;
  tmp[t] = v;
  __syncthreads();
  for (int off = 1; off < 256; off <<= 1) {
    int u = (t >= off) ? tmp[t - off] : 0;
    __syncthreads();
    tmp[t] += u;
    __syncthreads();
  }
  if (i < n) lscan[i] = tmp[t];
  if (t == 255) partials[blockIdx.x] = tmp[255];
}

// single block scans the (<=1024) block partials in LDS
__global__ void partial_scan_kernel(int* __restrict__ partials, int nb) {
  __shared__ int tmp[1024];
  int t = threadIdx.x;  // 256 threads
  for (int i = t; i < 1024; i += 256) tmp[i] = (i < nb) ? partials[i] : 0;
  __syncthreads();
  for (int off = 1; off < 1024; off <<= 1) {
    int u[4];
    for (int c = 0; c < 4; ++c) {
      int i = t + c * 256;
      u[c] = (i >= off) ? tmp[i - off] : 0;
    }
    __syncthreads();
    for (int c = 0; c < 4; ++c) tmp[t + c * 256] += u[c];
    __syncthreads();
  }
  for (int i = t; i < nb; i += 256) partials[i] = tmp[i];
}

__global__ void finalize_csr_kernel(const int* __restrict__ deg, const int* __restrict__ lscan,
                                    const int* __restrict__ partials, int* __restrict__ rowptr,
                                    int* __restrict__ cursor, int n, int E) {
  int i = blockIdx.x * 256 + threadIdx.x;
  if (i < n) {
    int off = (blockIdx.x > 0) ? partials[blockIdx.x - 1] : 0;
    int excl = off + lscan[i] - deg[i];
    rowptr[i] = excl;
    cursor[i] = excl;
  }
  if (i == 0) rowptr[n] = E;
}

__global__ void fill_csr_kernel(const int* __restrict__ src, const int* __restrict__ dst,
                                int* __restrict__ cursor, int* __restrict__ colidx, int E) {
  int e = blockIdx.x * 256 + threadIdx.x;
  if (e < E) {
    int p = atomicAdd(&cursor[dst[e]], 1);
    colidx[p] = src[e];
  }
}

__global__ void batch_count_kernel(const int* __restrict__ batch, int* __restrict__ gcnt, int N) {
  int i = blockIdx.x * 256 + threadIdx.x;
  if (i < N) atomicAdd(&gcnt[batch[i]], 1);
}

// ---------- weight prep: bf16, transposed Wt[n][k] with k-stride 136 (pad) ----------
__global__ void convert_weights_kernel(const float* __restrict__ W1, const float* __restrict__ W2,
                                       u16* __restrict__ W1t, u16* __restrict__ W2t, int L) {
  int idx = blockIdx.x * 256 + threadIdx.x;
  int total = L * D * D;
  if (idx >= total) return;
  int l = idx / (D * D);
  int rem = idx - l * (D * D);
  int nn = rem >> 7, kk = rem & 127;
  size_t s = (size_t)l * D * D + (size_t)kk * D + nn;
  size_t d = (size_t)l * 128 * 136 + (size_t)nn * 136 + kk;
  W1t[d] = f2bf(W1[s]);
  W2t[d] = f2bf(W2[s]);
}

// ---------- aggregation: z = h + sum_{j->i} h[j], written as bf16 ----------
// 8 gathers in flight per wave (4 independent accumulator chains) to break the
// serial load-latency chain that made round-1 latency-bound.
__global__ __launch_bounds__(256) void aggregate_kernel(
    const float* __restrict__ h, const int* __restrict__ rowptr,
    const int* __restrict__ colidx, u16* __restrict__ zb, int N) {
  int node = blockIdx.x * 4 + (threadIdx.x >> 6);
  if (node >= N) return;
  int lane = threadIdx.x & 63;
  const float2* hp = (const float2*)h;
  int s = rowptr[node], e = rowptr[node + 1];
  float2 a0 = hp[(size_t)node * 64 + lane];
  float2 a1 = {0.f, 0.f}, a2 = {0.f, 0.f}, a3 = {0.f, 0.f};
  int k = s;
  for (; k + 8 <= e; k += 8) {
    int j0 = colidx[k + 0], j1 = colidx[k + 1], j2 = colidx[k + 2], j3 = colidx[k + 3];
    int j4 = colidx[k + 4], j5 = colidx[k + 5], j6 = colidx[k + 6], j7 = colidx[k + 7];
    float2 v0 = hp[(size_t)j0 * 64 + lane];
    float2 v1 = hp[(size_t)j1 * 64 + lane];
    float2 v2 = hp[(size_t)j2 * 64 + lane];
    float2 v3 = hp[(size_t)j3 * 64 + lane];
    float2 v4 = hp[(size_t)j4 * 64 + lane];
    float2 v5 = hp[(size_t)j5 * 64 + lane];
    float2 v6 = hp[(size_t)j6 * 64 + lane];
    float2 v7 = hp[(size_t)j7 * 64 + lane];
    a0.x += v0.x; a0.y += v0.y; a1.x += v1.x; a1.y += v1.y;
    a2.x += v2.x; a2.y += v2.y; a3.x += v3.x; a3.y += v3.y;
    a0.x += v4.x; a0.y += v4.y; a1.x += v5.x; a1.y += v5.y;
    a2.x += v6.x; a2.y += v6.y; a3.x += v7.x; a3.y += v7.y;
  }
  for (; k + 2 <= e; k += 2) {
    int j0 = colidx[k], j1 = colidx[k + 1];
    float2 v0 = hp[(size_t)j0 * 64 + lane];
    float2 v1 = hp[(size_t)j1 * 64 + lane];
    a0.x += v0.x; a0.y += v0.y; a1.x += v1.x; a1.y += v1.y;
  }
  if (k < e) {
    int j = colidx[k];
    float2 v = hp[(size_t)j * 64 + lane];
    a0.x += v.x; a0.y += v.y;
  }
  float2 acc;
  acc.x = (a0.x + a1.x) + (a2.x + a3.x);
  acc.y = (a0.y + a1.y) + (a2.y + a3.y);
  ushort2 o; o.x = f2bf(acc.x); o.y = f2bf(acc.y);
  ((ushort2*)zb)[(size_t)node * 64 + lane] = o;
}

// ---------- fused GEMM + bias + relu (+ optional fused pooled dot) ----------
// A: [N,128] bf16 row-major. Wt: [128][136] bf16 (Wt[n][k] = W[k][n]).
// MODE 0: fp32 out (h).  MODE 1: bf16 out (y).  MODE 2: no h write; fused
// relu(h)·Wh dot per row, atomically accumulated into gsum[batch[row]].
template <int MODE>
__global__ __launch_bounds__(256) void mlp_gemm_kernel(
    const u16* __restrict__ A, const u16* __restrict__ Wt,
    const float* __restrict__ bias, void* __restrict__ out, int nrows,
    const float* __restrict__ Wh, const int* __restrict__ batch,
    float* __restrict__ gsum) {
  __shared__ __attribute__((aligned(16))) u16 ldsW[128 * 136];
  {
    const unsigned* s = (const unsigned*)Wt;
    unsigned* d = (unsigned*)ldsW;
    for (int i = threadIdx.x; i < 128 * 136 / 2; i += 256) d[i] = s[i];
  }
  __syncthreads();
  int wave = threadIdx.x >> 6, lane = threadIdx.x & 63;
  int quad = lane >> 4, l16 = lane & 15;
  int row0 = blockIdx.x * 64 + wave * 16;
  int mc = min(row0 + l16, nrows - 1);

  f32x4 acc[8];
  f32x4 zero = {0.f, 0.f, 0.f, 0.f};
#pragma unroll
  for (int nt = 0; nt < 8; ++nt) acc[nt] = zero;

#pragma unroll
  for (int kt = 0; kt < 4; ++kt) {
    short8 a = *(const short8*)(A + (size_t)mc * D + kt * 32 + quad * 8);
#pragma unroll
    for (int nt = 0; nt < 8; ++nt) {
      short8 b = *(const short8*)(ldsW + (nt * 16 + l16) * 136 + kt * 32 + quad * 8);
      acc[nt] = __builtin_amdgcn_mfma_f32_16x16x32_bf16(a, b, acc[nt], 0, 0, 0);
    }
  }

  if (MODE == 2) {
    float dotr[4] = {0.f, 0.f, 0.f, 0.f};
#pragma unroll
    for (int nt = 0; nt < 8; ++nt) {
      int col = nt * 16 + l16;
      float bv = bias[col];
      float wv = Wh[col];
#pragma unroll
      for (int r = 0; r < 4; ++r) {
        float v = fmaxf(acc[nt][r] + bv, 0.f);
        dotr[r] += v * wv;
      }
    }
    // reduce across the 16 lanes (l16) of each quad group
#pragma unroll
    for (int m = 1; m < 16; m <<= 1) {
#pragma unroll
      for (int r = 0; r < 4; ++r) dotr[r] += __shfl_xor(dotr[r], m, 64);
    }
    if (l16 == 0) {
#pragma unroll
      for (int r = 0; r < 4; ++r) {
        int row = row0 + quad * 4 + r;
        if (row < nrows) atomicAdd(&gsum[batch[row]], dotr[r]);
      }
    }
  } else {
#pragma unroll
    for (int nt = 0; nt < 8; ++nt) {
      int col = nt * 16 + l16;
      float bv = bias[col];
#pragma unroll
      for (int r = 0; r < 4; ++r) {
        int row = row0 + quad * 4 + r;
        if (row < nrows) {
          float v = fmaxf(acc[nt][r] + bv, 0.f);
          if (MODE == 1) ((u16*)out)[(size_t)row * D + col] = f2bf(v);
          else           ((float*)out)[(size_t)row * D + col] = v;
        }
      }
    }
  }
}

__global__ void pool_final_kernel(const float* __restrict__ gsum, const int* __restrict__ gcnt,
                                  const float* __restrict__ bh, float* __restrict__ out, int G) {
  int g = blockIdx.x * 256 + threadIdx.x;
  if (g < G) out[g] = gsum[g] / fmaxf((float)gcnt[g], 1.f) + bh[0];
}

extern "C" void kernel_launch(void* const* d_in, const int* in_sizes, int n_in,
                              void* d_out, int out_size, void* d_ws, size_t ws_size,
                              hipStream_t stream) {
  const float* x   = (const float*)d_in[0];
  const int* eidx  = (const int*)d_in[1];
  const int* batch = (const int*)d_in[2];
  const float* W1s = (const float*)d_in[3];
  const float* b1s = (const float*)d_in[4];
  const float* W2s = (const float*)d_in[5];
  const float* b2s = (const float*)d_in[6];
  const float* Wh  = (const float*)d_in[7];
  const float* bh  = (const float*)d_in[8];
  float* out = (float*)d_out;

  int N = in_sizes[0] / D;
  int E = in_sizes[1] / 2;
  int G = out_size;
  int L = in_sizes[3] / (D * D);

  const int* src = eidx;
  const int* dst = eidx + E;

  char* p = (char*)d_ws;
  auto alloc = [&](size_t b) { char* r = p; p += (b + 255) & ~(size_t)255; return r; };
  float* h      = (float*)alloc((size_t)N * D * 4);
  u16*   zb     = (u16*)  alloc((size_t)N * D * 2);
  u16*   y      = (u16*)  alloc((size_t)N * D * 2);
  int*   deg    = (int*)  alloc((size_t)N * 4);
  int*   lscan  = (int*)  alloc((size_t)N * 4);
  int*   rowptr = (int*)  alloc((size_t)(N + 1) * 4);
  int*   cursor = (int*)  alloc((size_t)N * 4);
  int*   colidx = (int*)  alloc((size_t)E * 4);
  int*   partials = (int*)alloc((size_t)1024 * 4);
  u16*   W1t    = (u16*)  alloc((size_t)L * 128 * 136 * 2);
  u16*   W2t    = (u16*)  alloc((size_t)L * 128 * 136 * 2);
  float* gsum   = (float*)alloc((size_t)G * 4);
  int*   gcnt   = (int*)  alloc((size_t)G * 4);

  hipMemsetAsync(deg, 0, (size_t)N * 4, stream);
  hipMemsetAsync(gsum, 0, (size_t)G * 4, stream);
  hipMemsetAsync(gcnt, 0, (size_t)G * 4, stream);

  int nScanBlocks = (N + 255) / 256;
  count_deg_kernel<<<(E + 255) / 256, 256, 0, stream>>>(dst, deg, E);
  block_scan_kernel<<<nScanBlocks, 256, 0, stream>>>(deg, lscan, partials, N);
  partial_scan_kernel<<<1, 256, 0, stream>>>(partials, nScanBlocks);
  finalize_csr_kernel<<<nScanBlocks, 256, 0, stream>>>(deg, lscan, partials, rowptr, cursor, N, E);
  fill_csr_kernel<<<(E + 255) / 256, 256, 0, stream>>>(src, dst, cursor, colidx, E);
  batch_count_kernel<<<(N + 255) / 256, 256, 0, stream>>>(batch, gcnt, N);
  convert_weights_kernel<<<(L * D * D + 255) / 256, 256, 0, stream>>>(W1s, W2s, W1t, W2t, L);

  int gemm_blocks = (N + 63) / 64;
  for (int l = 0; l < L; ++l) {
    const float* hin = (l == 0) ? x : h;
    aggregate_kernel<<<(N + 3) / 4, 256, 0, stream>>>(hin, rowptr, colidx, zb, N);
    mlp_gemm_kernel<1><<<gemm_blocks, 256, 0, stream>>>(
        zb, W1t + (size_t)l * 128 * 136, b1s + (size_t)l * D, (void*)y, N,
        nullptr, nullptr, nullptr);
    if (l < L - 1) {
      mlp_gemm_kernel<0><<<gemm_blocks, 256, 0, stream>>>(
          y, W2t + (size_t)l * 128 * 136, b2s + (size_t)l * D, (void*)h, N,
          nullptr, nullptr, nullptr);
    } else {
      mlp_gemm_kernel<2><<<gemm_blocks, 256, 0, stream>>>(
          y, W2t + (size_t)l * 128 * 136, b2s + (size_t)l * D, nullptr, N,
          Wh, batch, gsum);
    }
  }
  pool_final_kernel<<<(G + 255) / 256, 256, 0, stream>>>(gsum, gcnt, bh, out, G);
}